// Round 8
// baseline (1016.706 us; speedup 1.0000x reference)
//
#include <hip/hip_runtime.h>

// GraphConv: edge MLP (384->256->640, bf16 MFMA) + CSR-gather pool + obj MLP (256->256->128)
// Round 8: edge_mlp 2-phase pipeline — double-buffered B tiles AND A slices, STAGE(next)
// issued before MFMA(cur), ONE barrier per stage (T3 minimum-2-phase recipe). LDS 64KB,
// 2 blocks/CU, launch_bounds(256,2). Weights pre-swizzled tiles (rule #21) as in round 7.

using f32x4 = __attribute__((ext_vector_type(4))) float;
using s16x8 = __attribute__((ext_vector_type(8))) short;
typedef unsigned short u16x8 __attribute__((ext_vector_type(8)));

static __device__ __forceinline__ unsigned short f2b(float f) {
    unsigned int u = __float_as_uint(f);
    unsigned int r = (u + 0x7fffu + ((u >> 16) & 1u)) >> 16;  // RNE f32->bf16
    return (unsigned short)r;
}

static __device__ __forceinline__ float b2f(unsigned short b) {
    return __uint_as_float(((unsigned)b) << 16);
}

static __device__ __forceinline__ unsigned swz(unsigned row, unsigned byteoff) {
    return byteoff ^ ((row & 7u) << 4);
}

// async global->LDS, 16B/lane: per-lane global src, wave-uniform LDS dst (hw adds lane*16)
static __device__ __forceinline__ void gload_lds16(const unsigned short* g, unsigned short* l) {
    __builtin_amdgcn_global_load_lds(
        (const __attribute__((address_space(1))) unsigned int*)g,
        (__attribute__((address_space(3))) unsigned int*)l,
        16, 0, 0);
}

// ---------------- weight prep: bf16 + tiling + pre-swizzle ----------------
__global__ void prep_weights(const float* __restrict__ w1a, const float* __restrict__ w1b,
                             const float* __restrict__ w2a, const float* __restrict__ w2b,
                             unsigned short* __restrict__ w1aT, unsigned short* __restrict__ w1bT,
                             unsigned short* __restrict__ w2aT, unsigned short* __restrict__ w2bT) {
    int t = blockIdx.x * blockDim.x + threadIdx.x;
    if (t < 2 * 6 * 8192) {
        int tile = t >> 13; int nc1 = tile / 6, kt = tile % 6;
        int rem = t & 8191; int c = rem >> 6, kk = rem & 63;
        unsigned byte = ((unsigned)(c * 128 + kk * 2)) ^ ((c & 7u) << 4);
        *(unsigned short*)((char*)w1aT + (size_t)tile * 16384 + byte) =
            f2b(w1a[(size_t)(kt * 64 + kk) * 256 + nc1 * 128 + c]);
        return;
    }
    t -= 98304;
    if (t < 5 * 4 * 8192) {
        int tile = t >> 13; int nc = tile >> 2, kt2 = tile & 3;
        int rem = t & 8191; int c = rem >> 6, kk = rem & 63;
        unsigned byte = ((unsigned)(c * 128 + kk * 2)) ^ ((c & 7u) << 4);
        *(unsigned short*)((char*)w1bT + (size_t)tile * 16384 + byte) =
            f2b(w1b[(size_t)(kt2 * 64 + kk) * 640 + nc * 128 + c]);
        return;
    }
    t -= 163840;
    if (t < 65536) { int n = t >> 8, k = t & 255; w2aT[t] = f2b(w2a[k * 256 + n]); return; }
    t -= 65536;
    if (t < 32768) { int n = t >> 8, k = t & 255; w2bT[t] = f2b(w2b[k * 128 + n]); return; }
}

// ---------------- CSR build ----------------
__global__ void count_kernel_i(const int* __restrict__ edges, int* __restrict__ cnt, int T) {
    int e = blockIdx.x * blockDim.x + threadIdx.x;
    if (e < T) {
        atomicAdd(&cnt[edges[2 * (long long)e]], 1);
        atomicAdd(&cnt[edges[2 * (long long)e + 1]], 1);
    }
}

__global__ void scan_kernel(const int* __restrict__ cnt, int* __restrict__ rowptr,
                            int* __restrict__ cursor, int O) {
    __shared__ int sc[1024];
    const int tid = threadIdx.x;
    const int per = (O + 1023) >> 10;
    const int base = tid * per;
    int s = 0;
    for (int i = 0; i < per; ++i) { int j = base + i; if (j < O) s += cnt[j]; }
    sc[tid] = s;
    __syncthreads();
    for (int d = 1; d < 1024; d <<= 1) {
        int v = (tid >= d) ? sc[tid - d] : 0;
        __syncthreads();
        sc[tid] += v;
        __syncthreads();
    }
    int off = sc[tid] - s;
    for (int i = 0; i < per; ++i) {
        int j = base + i;
        if (j < O) { rowptr[j] = off; cursor[j] = off; off += cnt[j]; }
    }
    if (tid == 0) rowptr[O] = sc[1023];
}

__global__ void fill_kernel(const int* __restrict__ edges, int* __restrict__ cursor,
                            int* __restrict__ csr, int T) {
    int e = blockIdx.x * blockDim.x + threadIdx.x;
    if (e < T) {
        int s = edges[2 * (long long)e];
        int o = edges[2 * (long long)e + 1];
        int ps = atomicAdd(&cursor[s], 1); csr[ps] = e;
        int po = atomicAdd(&cursor[o], 1); csr[po] = T + e;
    }
}

// ---------------- edge MLP: 2-phase pipelined ----------------
__global__ __launch_bounds__(256, 2) void edge_mlp(
    const float* __restrict__ obj, const float* __restrict__ pred,
    const int* __restrict__ edges,
    const unsigned short* __restrict__ w1aT, const float* __restrict__ b1a,
    const unsigned short* __restrict__ w1bT, const float* __restrict__ b1b,
    unsigned short* __restrict__ edgeout, float* __restrict__ outP, int T) {
    const int m0 = blockIdx.x * 64;
    const int tid = threadIdx.x;
    const int lane = tid & 63, wid = tid >> 6;
    const int wm = wid >> 1, wn = wid & 1;
    const bool evenL = ((lane & 1) == 0);

    // LDS 64 KB: [0,32K) = A dbuf (8K @0, 8K @8192) then H [64][256] swizzled;
    //            [32K,64K) = B dbuf (16K @32768, 16K @49152)
    __shared__ unsigned short U[32768];
    char* const ldsb = (char*)U;
    unsigned short* const abuf0 = (unsigned short*)(ldsb);
    unsigned short* const abuf1 = (unsigned short*)(ldsb + 8192);
    unsigned short* const Hbuf  = (unsigned short*)(ldsb);
    unsigned short* const bbuf0 = (unsigned short*)(ldsb + 32768);
    unsigned short* const bbuf1 = (unsigned short*)(ldsb + 49152);

    bool okR[2][4];
    #pragma unroll
    for (int mi = 0; mi < 2; ++mi)
        #pragma unroll
        for (int rr = 0; rr < 4; ++rr)
            okR[mi][rr] = (m0 + wm * 32 + mi * 16 + ((lane >> 4) << 2) + rr) < T;

    const int r = tid >> 2;   // staging row 0..63
    const int q = tid & 3;
    int e_r = m0 + r; if (e_r >= T) e_r = T - 1;
    const int sIdx_r = edges[2 * (long long)e_r];
    const int oIdx_r = edges[2 * (long long)e_r + 1];

    // A-slice source for kt
    auto aSrc = [&](int kt) -> const float4* {
        const float* s;
        if (kt < 2)      s = obj  + (long long)sIdx_r * 128 + kt * 64;
        else if (kt < 4) s = pred + (long long)e_r   * 128 + (kt - 2) * 64;
        else             s = obj  + (long long)oIdx_r * 128 + (kt - 4) * 64;
        return (const float4*)s;
    };

    // stage one 16KB B tile (linear DMA; tile is pre-swizzled in global)
    auto stageB = [&](const unsigned short* gt, unsigned short* bb) {
        #pragma unroll
        for (int rr4 = 0; rr4 < 4; ++rr4) {
            unsigned off = wid * 4096u + rr4 * 1024u;
            gload_lds16((const unsigned short*)((const char*)gt + off + lane * 16u),
                        (unsigned short*)((char*)bb + off));
        }
    };

    // convert prefetched A regs -> swizzled LDS slice
    auto writeA = [&](const float4* ap, unsigned short* ab) {
        #pragma unroll
        for (int i = 0; i < 4; ++i) {
            float4 v = ap[i];
            ushort4 pk; pk.x = f2b(v.x); pk.y = f2b(v.y); pk.z = f2b(v.z); pk.w = f2b(v.w);
            unsigned byte = (r * 128u + q * 32u + i * 8u) ^ ((r & 7u) << 4);
            *(ushort4*)((char*)ab + byte) = pk;
        }
    };

    f32x4 acc1[2][2][4];
    #pragma unroll
    for (int a = 0; a < 2; ++a)
        #pragma unroll
        for (int b = 0; b < 2; ++b)
            #pragma unroll
            for (int c = 0; c < 4; ++c) acc1[a][b][c] = f32x4{0.f, 0.f, 0.f, 0.f};

    // 16-MFMA step for GEMM1 from (ab, bb) into acc1[nc1]
    auto mfma1 = [&](const unsigned short* ab, const unsigned short* bb, int nc1) {
        #pragma unroll
        for (int ks = 0; ks < 2; ++ks) {
            const unsigned kk = ks * 32u + ((lane >> 4) << 3);
            s16x8 af[2];
            #pragma unroll
            for (int mi = 0; mi < 2; ++mi) {
                unsigned row = wm * 32u + mi * 16u + (lane & 15);
                af[mi] = *(const s16x8*)((const char*)ab + ((row * 128u + kk * 2u) ^ ((row & 7u) << 4)));
            }
            #pragma unroll
            for (int nj = 0; nj < 4; ++nj) {
                unsigned c = wn * 64u + nj * 16u + (lane & 15);
                s16x8 bf = *(const s16x8*)((const char*)bb + ((c * 128u + kk * 2u) ^ ((c & 7u) << 4)));
                #pragma unroll
                for (int mi = 0; mi < 2; ++mi)
                    acc1[nc1][mi][nj] = __builtin_amdgcn_mfma_f32_16x16x32_bf16(af[mi], bf, acc1[nc1][mi][nj], 0, 0, 0);
            }
        }
    };

    // ---- GEMM1 prologue: A(0) + B(0,0) ----
    float4 ap[4];
    {
        const float4* s4 = aSrc(0);
        #pragma unroll
        for (int i = 0; i < 4; ++i) ap[i] = s4[q * 4 + i];
    }
    stageB(w1aT + (size_t)(0 * 6 + 0) * 8192, bbuf0);
    writeA(ap, abuf0);
    __syncthreads();

    // ---- GEMM1 main: 6 kt x 2 nc1, one barrier per stage ----
    #pragma unroll
    for (int kt = 0; kt < 6; ++kt) {
        unsigned short* const ab = (kt & 1) ? abuf1 : abuf0;
        // even stage (nc1=0): stage B(kt,1); issue A loads for kt+1; compute bbuf0
        stageB(w1aT + (size_t)(1 * 6 + kt) * 8192, bbuf1);
        if (kt < 5) {
            const float4* s4 = aSrc(kt + 1);
            #pragma unroll
            for (int i = 0; i < 4; ++i) ap[i] = s4[q * 4 + i];
        }
        mfma1(ab, bbuf0, 0);
        __syncthreads();
        // odd stage (nc1=1): stage B(kt+1,0); compute bbuf1; write A(kt+1)
        if (kt < 5) stageB(w1aT + (size_t)(0 * 6 + (kt + 1)) * 8192, bbuf0);
        mfma1(ab, bbuf1, 1);
        if (kt < 5) writeA(ap, (kt & 1) ? abuf0 : abuf1);
        __syncthreads();
    }

    // ---- transition: stage first GEMM2 tile, then write H ----
    stageB(w1bT, bbuf0);
    #pragma unroll
    for (int nb = 0; nb < 2; ++nb)
        #pragma unroll
        for (int nj = 0; nj < 4; ++nj) {
            int col = nb * 128 + wn * 64 + nj * 16 + (lane & 15);
            float bias = b1a[col];
            #pragma unroll
            for (int mi = 0; mi < 2; ++mi)
                #pragma unroll
                for (int rr = 0; rr < 4; ++rr) {
                    unsigned row = wm * 32u + mi * 16u + ((lane >> 4) << 2) + rr;
                    float v = acc1[nb][mi][nj][rr] + bias;
                    v = v > 0.f ? v : 0.f;
                    *(unsigned short*)((char*)Hbuf + swz(row, row * 512u + col * 2u)) = f2b(v);
                }
        }
    __syncthreads();

    // ---- GEMM2: 5 nc x 4 kt2 stages, dbuf parity = kt2&1 ----
    #pragma unroll
    for (int nc = 0; nc < 5; ++nc) {
        f32x4 acc2[2][4];
        #pragma unroll
        for (int b = 0; b < 2; ++b)
            #pragma unroll
            for (int c = 0; c < 4; ++c) acc2[b][c] = f32x4{0.f, 0.f, 0.f, 0.f};

        #pragma unroll
        for (int kt2 = 0; kt2 < 4; ++kt2) {
            // stage next tile
            if (kt2 < 3)           stageB(w1bT + (size_t)(nc * 4 + kt2 + 1) * 8192, (kt2 & 1) ? bbuf0 : bbuf1);
            else if (nc < 4)       stageB(w1bT + (size_t)((nc + 1) * 4) * 8192, bbuf0);
            unsigned short* const bb = (kt2 & 1) ? bbuf1 : bbuf0;
            #pragma unroll
            for (int ks = 0; ks < 2; ++ks) {
                const unsigned kkB = ks * 32u + ((lane >> 4) << 3);
                const unsigned kkH = kt2 * 64u + kkB;
                s16x8 af[2];
                #pragma unroll
                for (int mi = 0; mi < 2; ++mi) {
                    unsigned row = wm * 32u + mi * 16u + (lane & 15);
                    af[mi] = *(const s16x8*)((const char*)Hbuf + swz(row, row * 512u + kkH * 2u));
                }
                #pragma unroll
                for (int nj = 0; nj < 4; ++nj) {
                    unsigned c = wn * 64u + nj * 16u + (lane & 15);
                    s16x8 bf = *(const s16x8*)((const char*)bb + ((c * 128u + kkB * 2u) ^ ((c & 7u) << 4)));
                    #pragma unroll
                    for (int mi = 0; mi < 2; ++mi)
                        acc2[mi][nj] = __builtin_amdgcn_mfma_f32_16x16x32_bf16(af[mi], bf, acc2[mi][nj], 0, 0, 0);
                }
            }
            __syncthreads();
        }

        // epilogue chunk nc (register-only inputs; stores fire-and-forget)
        if (nc == 2) {
            #pragma unroll
            for (int nj = 0; nj < 4; ++nj) {
                int col = nc * 128 + wn * 64 + nj * 16 + (lane & 15);
                float bias = b1b[col];
                #pragma unroll
                for (int mi = 0; mi < 2; ++mi)
                    #pragma unroll
                    for (int rr = 0; rr < 4; ++rr) {
                        int row = wm * 32 + mi * 16 + ((lane >> 4) << 2) + rr;
                        if (okR[mi][rr]) {
                            float v = acc2[mi][nj][rr] + bias;
                            v = v > 0.f ? v : 0.f;
                            outP[(long long)(m0 + row) * 128 + (col - 256)] = v;
                        }
                    }
            }
        } else {
            #pragma unroll
            for (int nj = 0; nj < 4; ++nj) {
                int col = nc * 128 + wn * 64 + nj * 16 + (lane & 15);
                float bias = b1b[col];
                int pc = (nc < 2) ? col : (col - 384);
                int pcb = (lane & 1) ? (pc - 1) : pc;
                #pragma unroll
                for (int mi = 0; mi < 2; ++mi) {
                    float vv[4];
                    #pragma unroll
                    for (int rr = 0; rr < 4; ++rr) {
                        float v = acc2[mi][nj][rr] + bias;
                        vv[rr] = v > 0.f ? v : 0.f;
                    }
                    float nb0 = __shfl_xor(vv[0], 1);
                    float nb1 = __shfl_xor(vv[1], 1);
                    float nb2 = __shfl_xor(vv[2], 1);
                    float nb3 = __shfl_xor(vv[3], 1);
                    #pragma unroll
                    for (int k = 0; k < 2; ++k) {
                        float lo = evenL ? (k ? vv[1] : vv[0]) : (k ? nb3 : nb2);
                        float hi = evenL ? (k ? nb1 : nb0) : (k ? vv[3] : vv[2]);
                        int rsel = evenL ? k : 2 + k;
                        if (okR[mi][rsel]) {
                            int row = wm * 32 + mi * 16 + ((lane >> 4) << 2) + rsel;
                            size_t e = (size_t)(m0 + row);
                            size_t rid = (nc < 2) ? e : (size_t)T + e;
                            unsigned pk = ((unsigned)f2b(hi) << 16) | f2b(lo);
                            *(unsigned*)(edgeout + rid * 256 + pcb) = pk;
                        }
                    }
                }
            }
        }
    }
}

// ---------------- CSR gather ----------------
__global__ __launch_bounds__(256, 4) void pool_gather(
    const unsigned short* __restrict__ edgeout, const int* __restrict__ rowptr,
    const int* __restrict__ csr, unsigned short* __restrict__ pooled, int O) {
    int w = blockIdx.x * 4 + (threadIdx.x >> 6);
    if (w >= O) return;
    const int lane = threadIdx.x & 63;
    const int beg = rowptr[w], end = rowptr[w + 1];
    float ax = 0.f, ay = 0.f, az = 0.f, aw = 0.f;
    float bx = 0.f, by = 0.f, bz = 0.f, bw = 0.f;
    int i = beg;
    for (; i + 1 < end; i += 2) {
        int r0 = csr[i], r1 = csr[i + 1];
        ushort4 v0 = *(const ushort4*)(edgeout + (size_t)r0 * 256 + lane * 4);
        ushort4 v1 = *(const ushort4*)(edgeout + (size_t)r1 * 256 + lane * 4);
        ax += b2f(v0.x); ay += b2f(v0.y); az += b2f(v0.z); aw += b2f(v0.w);
        bx += b2f(v1.x); by += b2f(v1.y); bz += b2f(v1.z); bw += b2f(v1.w);
    }
    if (i < end) {
        int r0 = csr[i];
        ushort4 v0 = *(const ushort4*)(edgeout + (size_t)r0 * 256 + lane * 4);
        ax += b2f(v0.x); ay += b2f(v0.y); az += b2f(v0.z); aw += b2f(v0.w);
    }
    float inv = 1.f / fmaxf((float)(end - beg), 1.f);
    ushort4 o4;
    o4.x = f2b((ax + bx) * inv); o4.y = f2b((ay + by) * inv);
    o4.z = f2b((az + bz) * inv); o4.w = f2b((aw + bw) * inv);
    *(ushort4*)(pooled + (size_t)w * 256 + lane * 4) = o4;
}

// ---------------- object MLP ----------------
__global__ __launch_bounds__(256, 2) void obj_mlp(
    const unsigned short* __restrict__ pooled,
    const unsigned short* __restrict__ w2aT, const float* __restrict__ b2a,
    const unsigned short* __restrict__ w2bT, const float* __restrict__ b2b,
    float* __restrict__ outObj, int O) {
    const int m0 = blockIdx.x * 64;
    const int tid = threadIdx.x;
    const int lane = tid & 63, wid = tid >> 6;
    const int wm = wid >> 1, wn = wid & 1;

    __shared__ unsigned short Abuf[64 * 256];

    {
        const int r = tid >> 2, q = tid & 3;
        int objc = m0 + r; if (objc >= O) objc = O - 1;
        const u16x8* s8 = (const u16x8*)(pooled + (size_t)objc * 256);
        #pragma unroll
        for (int i = 0; i < 8; ++i) {
            u16x8 v = s8[q * 8 + i];
            unsigned byte = r * 512u + (q * 64u + i * 8u) * 2u;
            *(u16x8*)((char*)Abuf + swz(r, byte)) = v;
        }
    }
    __syncthreads();

    f32x4 acc1[2][2][4];
    #pragma unroll
    for (int a = 0; a < 2; ++a)
        #pragma unroll
        for (int b = 0; b < 2; ++b)
            #pragma unroll
            for (int c = 0; c < 4; ++c) acc1[a][b][c] = f32x4{0.f, 0.f, 0.f, 0.f};
    #pragma unroll
    for (int ks = 0; ks < 8; ++ks) {
        const int klane = ks * 32 + ((lane >> 4) << 3);
        s16x8 af[2];
        #pragma unroll
        for (int mi = 0; mi < 2; ++mi) {
            int row = wm * 32 + mi * 16 + (lane & 15);
            af[mi] = *(const s16x8*)((const char*)Abuf + swz(row, row * 512u + klane * 2u));
        }
        #pragma unroll
        for (int nb = 0; nb < 2; ++nb)
            #pragma unroll
            for (int nj = 0; nj < 4; ++nj) {
                int col = nb * 128 + wn * 64 + nj * 16 + (lane & 15);
                s16x8 bf = *(const s16x8*)(w2aT + (long long)col * 256 + klane);
                #pragma unroll
                for (int mi = 0; mi < 2; ++mi)
                    acc1[nb][mi][nj] = __builtin_amdgcn_mfma_f32_16x16x32_bf16(af[mi], bf, acc1[nb][mi][nj], 0, 0, 0);
            }
    }
    __syncthreads();

    #pragma unroll
    for (int nb = 0; nb < 2; ++nb)
        #pragma unroll
        for (int nj = 0; nj < 4; ++nj) {
            int col = nb * 128 + wn * 64 + nj * 16 + (lane & 15);
            float bias = b2a[col];
            #pragma unroll
            for (int mi = 0; mi < 2; ++mi)
                #pragma unroll
                for (int rr = 0; rr < 4; ++rr) {
                    int row = wm * 32 + mi * 16 + ((lane >> 4) << 2) + rr;
                    float v = acc1[nb][mi][nj][rr] + bias;
                    v = v > 0.f ? v : 0.f;
                    *(unsigned short*)((char*)Abuf + swz(row, row * 512u + col * 2u)) = f2b(v);
                }
        }
    __syncthreads();

    f32x4 acc2[2][4];
    #pragma unroll
    for (int b = 0; b < 2; ++b)
        #pragma unroll
        for (int c = 0; c < 4; ++c) acc2[b][c] = f32x4{0.f, 0.f, 0.f, 0.f};
    #pragma unroll
    for (int ks = 0; ks < 8; ++ks) {
        const int klane = ks * 32 + ((lane >> 4) << 3);
        s16x8 af[2];
        #pragma unroll
        for (int mi = 0; mi < 2; ++mi) {
            int row = wm * 32 + mi * 16 + (lane & 15);
            af[mi] = *(const s16x8*)((const char*)Abuf + swz(row, row * 512u + klane * 2u));
        }
        #pragma unroll
        for (int nj = 0; nj < 4; ++nj) {
            int col = wn * 64 + nj * 16 + (lane & 15);
            s16x8 bf = *(const s16x8*)(w2bT + (long long)col * 256 + klane);
            #pragma unroll
            for (int mi = 0; mi < 2; ++mi)
                acc2[mi][nj] = __builtin_amdgcn_mfma_f32_16x16x32_bf16(af[mi], bf, acc2[mi][nj], 0, 0, 0);
        }
    }

    #pragma unroll
    for (int nj = 0; nj < 4; ++nj) {
        int col = wn * 64 + nj * 16 + (lane & 15);
        float bias = b2b[col];
        #pragma unroll
        for (int mi = 0; mi < 2; ++mi)
            #pragma unroll
            for (int rr = 0; rr < 4; ++rr) {
                int row = wm * 32 + mi * 16 + ((lane >> 4) << 2) + rr;
                int o = m0 + row;
                if (o < O) {
                    float v = acc2[mi][nj][rr] + bias;
                    v = v > 0.f ? v : 0.f;
                    outObj[(long long)o * 128 + col] = v;
                }
            }
    }
}

extern "C" void kernel_launch(void* const* d_in, const int* in_sizes, int n_in,
                              void* d_out, int out_size, void* d_ws, size_t ws_size,
                              hipStream_t stream) {
    const float* obj  = (const float*)d_in[0];
    const float* pred = (const float*)d_in[1];
    const int*   edges = (const int*)d_in[2];
    const float* w1a = (const float*)d_in[3];
    const float* b1a = (const float*)d_in[4];
    const float* w1b = (const float*)d_in[5];
    const float* b1b = (const float*)d_in[6];
    const float* w2a = (const float*)d_in[7];
    const float* b2a = (const float*)d_in[8];
    const float* w2b = (const float*)d_in[9];
    const float* b2b = (const float*)d_in[10];

    const int O = in_sizes[0] / 128;
    const int T = in_sizes[1] / 128;

    auto al = [](size_t x) { return (x + 255) & ~(size_t)255; };
    const size_t szEdgeout = (size_t)2 * T * 256 * 2;
    const size_t szPooled  = (size_t)O * 256 * 2;
    const size_t szCnt     = (size_t)O * 4;
    const size_t szRow     = (size_t)(O + 1) * 4;
    const size_t szCsr     = (size_t)2 * T * 4;

    size_t off = 0;
    char* ws = (char*)d_ws;
    unsigned short* edgeout = (unsigned short*)(ws + off); off += al(szEdgeout);
    unsigned short* pooled  = (unsigned short*)(ws + off); off += al(szPooled);
    int* cnt    = (int*)(ws + off); off += al(szCnt);
    int* cursor = (int*)(ws + off); off += al(szCnt);
    int* rowptr = (int*)(ws + off); off += al(szRow);
    int* csr    = (int*)(ws + off); off += al(szCsr);
    unsigned short* w1aT = (unsigned short*)(ws + off); off += (size_t)12 * 8192 * 2;
    unsigned short* w1bT = (unsigned short*)(ws + off); off += (size_t)20 * 8192 * 2;
    unsigned short* w2aT = (unsigned short*)(ws + off); off += (size_t)256 * 256 * 2;
    unsigned short* w2bT = (unsigned short*)(ws + off);

    float* outObj = (float*)d_out;
    float* outP   = (float*)d_out + (size_t)O * 128;

    hipMemsetAsync(cnt, 0, szCnt, stream);
    const int prepElems = 98304 + 163840 + 65536 + 32768;
    prep_weights<<<(prepElems + 255) / 256, 256, 0, stream>>>(w1a, w1b, w2a, w2b, w1aT, w1bT, w2aT, w2bT);
    count_kernel_i<<<(T + 255) / 256, 256, 0, stream>>>(edges, cnt, T);
    scan_kernel<<<1, 1024, 0, stream>>>(cnt, rowptr, cursor, O);
    fill_kernel<<<(T + 255) / 256, 256, 0, stream>>>(edges, cursor, csr, T);
    edge_mlp<<<(T + 63) / 64, 256, 0, stream>>>(obj, pred, edges, w1aT, b1a, w1bT, b1b, edgeout, outP, T);
    pool_gather<<<(O + 3) / 4, 256, 0, stream>>>(edgeout, rowptr, csr, pooled, O);
    obj_mlp<<<(O + 63) / 64, 256, 0, stream>>>(pooled, w2aT, b2a, w2bT, b2b, outObj, O);
}

// Round 9
// 1002.622 us; speedup vs baseline: 1.0140x; 1.0140x over previous
//
#include <hip/hip_runtime.h>

// GraphConv: edge MLP (384->256->640, bf16 MFMA) + CSR-gather pool + obj MLP (256->256->128)
// Round 9: edge_mlp rebuilt at BM=128, 512 threads (8 waves 2x4). Stages are 32KB B-tiles,
// 32 MFMA/wave/stage (compute now covers the vmcnt(0)-before-barrier drain). 16 stages/block.
// LDS 128KB: H[128][256] (A-dbuf unioned) + B-dbuf 2x32KB. Weights pre-swizzled (rule #21).

using f32x4 = __attribute__((ext_vector_type(4))) float;
using s16x8 = __attribute__((ext_vector_type(8))) short;
typedef unsigned short u16x8 __attribute__((ext_vector_type(8)));

static __device__ __forceinline__ unsigned short f2b(float f) {
    unsigned int u = __float_as_uint(f);
    unsigned int r = (u + 0x7fffu + ((u >> 16) & 1u)) >> 16;  // RNE f32->bf16
    return (unsigned short)r;
}

static __device__ __forceinline__ float b2f(unsigned short b) {
    return __uint_as_float(((unsigned)b) << 16);
}

static __device__ __forceinline__ unsigned swz(unsigned row, unsigned byteoff) {
    return byteoff ^ ((row & 7u) << 4);
}

static __device__ __forceinline__ void gload_lds16(const unsigned short* g, unsigned short* l) {
    __builtin_amdgcn_global_load_lds(
        (const __attribute__((address_space(1))) unsigned int*)g,
        (__attribute__((address_space(3))) unsigned int*)l,
        16, 0, 0);
}

// ---------------- weight prep ----------------
// w1aT: 6 tiles (kt) of [256c][64k] bf16 (32KB), byte=(c*128+kk*2)^((c&7)<<4)
// w1bT: 10 tiles (nc*2+kh) of [128c][128k] bf16 (32KB), byte=(c*256+kk*2)^((c&7)<<4)
// w2aT/w2bT: plain [n][k] transpose.
__global__ void prep_weights(const float* __restrict__ w1a, const float* __restrict__ w1b,
                             const float* __restrict__ w2a, const float* __restrict__ w2b,
                             unsigned short* __restrict__ w1aT, unsigned short* __restrict__ w1bT,
                             unsigned short* __restrict__ w2aT, unsigned short* __restrict__ w2bT) {
    int t = blockIdx.x * blockDim.x + threadIdx.x;
    if (t < 6 * 16384) {
        int kt = t >> 14;
        int rem = t & 16383; int c = rem >> 6, kk = rem & 63;   // c 0..255, kk 0..63
        unsigned byte = ((unsigned)(c * 128 + kk * 2)) ^ ((c & 7u) << 4);
        *(unsigned short*)((char*)w1aT + (size_t)kt * 32768 + byte) =
            f2b(w1a[(size_t)(kt * 64 + kk) * 256 + c]);
        return;
    }
    t -= 98304;
    if (t < 10 * 16384) {
        int tile = t >> 14; int nc = tile >> 1, kh = tile & 1;
        int rem = t & 16383; int c = rem >> 7, kk = rem & 127;  // c 0..127, kk 0..127
        unsigned byte = ((unsigned)(c * 256 + kk * 2)) ^ ((c & 7u) << 4);
        *(unsigned short*)((char*)w1bT + (size_t)tile * 32768 + byte) =
            f2b(w1b[(size_t)(kh * 128 + kk) * 640 + nc * 128 + c]);
        return;
    }
    t -= 163840;
    if (t < 65536) { int n = t >> 8, k = t & 255; w2aT[t] = f2b(w2a[k * 256 + n]); return; }
    t -= 65536;
    if (t < 32768) { int n = t >> 8, k = t & 255; w2bT[t] = f2b(w2b[k * 128 + n]); return; }
}

// ---------------- CSR build ----------------
__global__ void count_kernel_i(const int* __restrict__ edges, int* __restrict__ cnt, int T) {
    int e = blockIdx.x * blockDim.x + threadIdx.x;
    if (e < T) {
        atomicAdd(&cnt[edges[2 * (long long)e]], 1);
        atomicAdd(&cnt[edges[2 * (long long)e + 1]], 1);
    }
}

__global__ void scan_kernel(const int* __restrict__ cnt, int* __restrict__ rowptr,
                            int* __restrict__ cursor, int O) {
    __shared__ int sc[1024];
    const int tid = threadIdx.x;
    const int per = (O + 1023) >> 10;
    const int base = tid * per;
    int s = 0;
    for (int i = 0; i < per; ++i) { int j = base + i; if (j < O) s += cnt[j]; }
    sc[tid] = s;
    __syncthreads();
    for (int d = 1; d < 1024; d <<= 1) {
        int v = (tid >= d) ? sc[tid - d] : 0;
        __syncthreads();
        sc[tid] += v;
        __syncthreads();
    }
    int off = sc[tid] - s;
    for (int i = 0; i < per; ++i) {
        int j = base + i;
        if (j < O) { rowptr[j] = off; cursor[j] = off; off += cnt[j]; }
    }
    if (tid == 0) rowptr[O] = sc[1023];
}

__global__ void fill_kernel(const int* __restrict__ edges, int* __restrict__ cursor,
                            int* __restrict__ csr, int T) {
    int e = blockIdx.x * blockDim.x + threadIdx.x;
    if (e < T) {
        int s = edges[2 * (long long)e];
        int o = edges[2 * (long long)e + 1];
        int ps = atomicAdd(&cursor[s], 1); csr[ps] = e;
        int po = atomicAdd(&cursor[o], 1); csr[po] = T + e;
    }
}

// ---------------- edge MLP: BM=128, 512 threads, 8 waves (2x4) ----------------
__global__ __launch_bounds__(512, 2) void edge_mlp(
    const float* __restrict__ obj, const float* __restrict__ pred,
    const int* __restrict__ edges,
    const unsigned short* __restrict__ w1aT, const float* __restrict__ b1a,
    const unsigned short* __restrict__ w1bT, const float* __restrict__ b1b,
    unsigned short* __restrict__ edgeout, float* __restrict__ outP, int T) {
    const int m0 = blockIdx.x * 128;
    const int tid = threadIdx.x;
    const int lane = tid & 63, wid = tid >> 6;
    const int wm = wid >> 2, wn = wid & 3;      // 2 row-halves x 4 col-quarters
    const bool evenL = ((lane & 1) == 0);

    // LDS 128 KB:
    //   [0, 64K)    H [128][256] bf16 swizzled (stride 512B); A dbuf (2x16KB) unioned at [0,32K)
    //   [64K, 96K)  bbuf0 (32KB)   [96K, 128K) bbuf1 (32KB)
    __shared__ unsigned short U[65536];
    char* const ldsb = (char*)U;
    unsigned short* const abuf0 = (unsigned short*)(ldsb);
    unsigned short* const abuf1 = (unsigned short*)(ldsb + 16384);
    unsigned short* const Hbuf  = (unsigned short*)(ldsb);
    unsigned short* const bbuf0 = (unsigned short*)(ldsb + 65536);
    unsigned short* const bbuf1 = (unsigned short*)(ldsb + 98304);

    bool okR[4][4];
    #pragma unroll
    for (int mi = 0; mi < 4; ++mi)
        #pragma unroll
        for (int rr = 0; rr < 4; ++rr)
            okR[mi][rr] = (m0 + wm * 64 + mi * 16 + ((lane >> 4) << 2) + rr) < T;

    const int r = tid >> 2;   // staging row 0..127
    const int q = tid & 3;
    int e_r = m0 + r; if (e_r >= T) e_r = T - 1;
    const int sIdx_r = edges[2 * (long long)e_r];
    const int oIdx_r = edges[2 * (long long)e_r + 1];

    // A-slice (kt): 128 rows x 64 k
    auto aSrc = [&](int kt) -> const float4* {
        const float* s;
        if (kt < 2)      s = obj  + (long long)sIdx_r * 128 + kt * 64;
        else if (kt < 4) s = pred + (long long)e_r   * 128 + (kt - 2) * 64;
        else             s = obj  + (long long)oIdx_r * 128 + (kt - 4) * 64;
        return (const float4*)s;
    };

    // stage one 32KB tile: 512 threads x 16B x 4 rounds
    auto stageB = [&](const unsigned short* gt, unsigned short* bb) {
        #pragma unroll
        for (int rr4 = 0; rr4 < 4; ++rr4) {
            unsigned off = wid * 4096u + rr4 * 1024u;   // hmm: 8 waves*4096=32768 ✓
            gload_lds16((const unsigned short*)((const char*)gt + off + lane * 16u),
                        (unsigned short*)((char*)bb + off));
        }
    };

    auto writeA = [&](const float4* ap, unsigned short* ab) {
        #pragma unroll
        for (int i = 0; i < 4; ++i) {
            float4 v = ap[i];
            ushort4 pk; pk.x = f2b(v.x); pk.y = f2b(v.y); pk.z = f2b(v.z); pk.w = f2b(v.w);
            unsigned byte = (r * 128u + q * 32u + i * 8u) ^ ((r & 7u) << 4);
            *(ushort4*)((char*)ab + byte) = pk;
        }
    };

    f32x4 acc1[4][4];   // 64 rows x 64 cols per wave
    #pragma unroll
    for (int a = 0; a < 4; ++a)
        #pragma unroll
        for (int b = 0; b < 4; ++b) acc1[a][b] = f32x4{0.f, 0.f, 0.f, 0.f};

    auto mfma1 = [&](const unsigned short* ab, const unsigned short* bb) {
        #pragma unroll
        for (int ks = 0; ks < 2; ++ks) {
            const unsigned kk = ks * 32u + ((lane >> 4) << 3);
            s16x8 af[4];
            #pragma unroll
            for (int mi = 0; mi < 4; ++mi) {
                unsigned row = wm * 64u + mi * 16u + (lane & 15);
                af[mi] = *(const s16x8*)((const char*)ab + ((row * 128u + kk * 2u) ^ ((row & 7u) << 4)));
            }
            #pragma unroll
            for (int nj = 0; nj < 4; ++nj) {
                unsigned c = wn * 64u + nj * 16u + (lane & 15);
                s16x8 bf = *(const s16x8*)((const char*)bb + ((c * 128u + kk * 2u) ^ ((c & 7u) << 4)));
                #pragma unroll
                for (int mi = 0; mi < 4; ++mi)
                    acc1[mi][nj] = __builtin_amdgcn_mfma_f32_16x16x32_bf16(af[mi], bf, acc1[mi][nj], 0, 0, 0);
            }
        }
    };

    // ---- GEMM1 prologue ----
    float4 ap[4];
    {
        const float4* s4 = aSrc(0);
        #pragma unroll
        for (int i = 0; i < 4; ++i) ap[i] = s4[q * 4 + i];
    }
    stageB(w1aT, bbuf0);
    writeA(ap, abuf0);
    __syncthreads();

    // ---- GEMM1: 6 kt stages, 32 MFMA/wave each ----
    #pragma unroll
    for (int kt = 0; kt < 6; ++kt) {
        if (kt < 5) {
            const float4* s4 = aSrc(kt + 1);          // A loads FIRST (older in vmcnt FIFO)
            #pragma unroll
            for (int i = 0; i < 4; ++i) ap[i] = s4[q * 4 + i];
            stageB(w1aT + (size_t)(kt + 1) * 16384, ((kt + 1) & 1) ? bbuf1 : bbuf0);
        }
        mfma1((kt & 1) ? abuf1 : abuf0, (kt & 1) ? bbuf1 : bbuf0);
        if (kt < 5) writeA(ap, ((kt + 1) & 1) ? abuf1 : abuf0);
        __syncthreads();
    }

    // ---- transition: stage first GEMM2 tile; write H ----
    stageB(w1bT, bbuf0);
    #pragma unroll
    for (int nj = 0; nj < 4; ++nj) {
        int col = wn * 64 + nj * 16 + (lane & 15);
        float bias = b1a[col];
        #pragma unroll
        for (int mi = 0; mi < 4; ++mi)
            #pragma unroll
            for (int rr = 0; rr < 4; ++rr) {
                unsigned row = wm * 64u + mi * 16u + ((lane >> 4) << 2) + rr;
                float v = acc1[mi][nj][rr] + bias;
                v = v > 0.f ? v : 0.f;
                *(unsigned short*)((char*)Hbuf + swz(row, row * 512u + col * 2u)) = f2b(v);
            }
    }
    __syncthreads();

    // ---- GEMM2: 5 nc x 2 kh stages (32KB each), epilogue per nc ----
    #pragma unroll
    for (int nc = 0; nc < 5; ++nc) {
        f32x4 acc2[4][2];
        #pragma unroll
        for (int a = 0; a < 4; ++a)
            #pragma unroll
            for (int b = 0; b < 2; ++b) acc2[a][b] = f32x4{0.f, 0.f, 0.f, 0.f};

        #pragma unroll
        for (int kh = 0; kh < 2; ++kh) {
            const int t10 = nc * 2 + kh;
            if (t10 < 9) stageB(w1bT + (size_t)(t10 + 1) * 16384, ((t10 + 1) & 1) ? bbuf1 : bbuf0);
            const unsigned short* bb = (t10 & 1) ? bbuf1 : bbuf0;
            #pragma unroll
            for (int ks = 0; ks < 4; ++ks) {
                const unsigned kkB = ks * 32u + ((lane >> 4) << 3);
                const unsigned kkH = kh * 128u + kkB;
                s16x8 af[4];
                #pragma unroll
                for (int mi = 0; mi < 4; ++mi) {
                    unsigned row = wm * 64u + mi * 16u + (lane & 15);
                    af[mi] = *(const s16x8*)((const char*)Hbuf + swz(row, row * 512u + kkH * 2u));
                }
                #pragma unroll
                for (int nj = 0; nj < 2; ++nj) {
                    unsigned c = wn * 32u + nj * 16u + (lane & 15);
                    s16x8 bf = *(const s16x8*)((const char*)bb + ((c * 256u + kkB * 2u) ^ ((c & 7u) << 4)));
                    #pragma unroll
                    for (int mi = 0; mi < 4; ++mi)
                        acc2[mi][nj] = __builtin_amdgcn_mfma_f32_16x16x32_bf16(af[mi], bf, acc2[mi][nj], 0, 0, 0);
                }
            }
            __syncthreads();
        }

        // epilogue nc (register-only inputs)
        if (nc == 2) {
            #pragma unroll
            for (int nj = 0; nj < 2; ++nj) {
                int col = nc * 128 + wn * 32 + nj * 16 + (lane & 15);
                float bias = b1b[col];
                #pragma unroll
                for (int mi = 0; mi < 4; ++mi)
                    #pragma unroll
                    for (int rr = 0; rr < 4; ++rr) {
                        int row = wm * 64 + mi * 16 + ((lane >> 4) << 2) + rr;
                        if (okR[mi][rr]) {
                            float v = acc2[mi][nj][rr] + bias;
                            v = v > 0.f ? v : 0.f;
                            outP[(long long)(m0 + row) * 128 + (col - 256)] = v;
                        }
                    }
            }
        } else {
            #pragma unroll
            for (int nj = 0; nj < 2; ++nj) {
                int col = nc * 128 + wn * 32 + nj * 16 + (lane & 15);
                float bias = b1b[col];
                int pc = (nc < 2) ? col : (col - 384);
                int pcb = (lane & 1) ? (pc - 1) : pc;
                #pragma unroll
                for (int mi = 0; mi < 4; ++mi) {
                    float vv[4];
                    #pragma unroll
                    for (int rr = 0; rr < 4; ++rr) {
                        float v = acc2[mi][nj][rr] + bias;
                        vv[rr] = v > 0.f ? v : 0.f;
                    }
                    float nb0 = __shfl_xor(vv[0], 1);
                    float nb1 = __shfl_xor(vv[1], 1);
                    float nb2 = __shfl_xor(vv[2], 1);
                    float nb3 = __shfl_xor(vv[3], 1);
                    #pragma unroll
                    for (int k = 0; k < 2; ++k) {
                        float lo = evenL ? (k ? vv[1] : vv[0]) : (k ? nb3 : nb2);
                        float hi = evenL ? (k ? nb1 : nb0) : (k ? vv[3] : vv[2]);
                        int rsel = evenL ? k : 2 + k;
                        if (okR[mi][rsel]) {
                            int row = wm * 64 + mi * 16 + ((lane >> 4) << 2) + rsel;
                            size_t e = (size_t)(m0 + row);
                            size_t rid = (nc < 2) ? e : (size_t)T + e;
                            unsigned pk = ((unsigned)f2b(hi) << 16) | f2b(lo);
                            *(unsigned*)(edgeout + rid * 256 + pcb) = pk;
                        }
                    }
                }
            }
        }
    }
}

// ---------------- CSR gather ----------------
__global__ __launch_bounds__(256, 4) void pool_gather(
    const unsigned short* __restrict__ edgeout, const int* __restrict__ rowptr,
    const int* __restrict__ csr, unsigned short* __restrict__ pooled, int O) {
    int w = blockIdx.x * 4 + (threadIdx.x >> 6);
    if (w >= O) return;
    const int lane = threadIdx.x & 63;
    const int beg = rowptr[w], end = rowptr[w + 1];
    float ax = 0.f, ay = 0.f, az = 0.f, aw = 0.f;
    float bx = 0.f, by = 0.f, bz = 0.f, bw = 0.f;
    int i = beg;
    for (; i + 1 < end; i += 2) {
        int r0 = csr[i], r1 = csr[i + 1];
        ushort4 v0 = *(const ushort4*)(edgeout + (size_t)r0 * 256 + lane * 4);
        ushort4 v1 = *(const ushort4*)(edgeout + (size_t)r1 * 256 + lane * 4);
        ax += b2f(v0.x); ay += b2f(v0.y); az += b2f(v0.z); aw += b2f(v0.w);
        bx += b2f(v1.x); by += b2f(v1.y); bz += b2f(v1.z); bw += b2f(v1.w);
    }
    if (i < end) {
        int r0 = csr[i];
        ushort4 v0 = *(const ushort4*)(edgeout + (size_t)r0 * 256 + lane * 4);
        ax += b2f(v0.x); ay += b2f(v0.y); az += b2f(v0.z); aw += b2f(v0.w);
    }
    float inv = 1.f / fmaxf((float)(end - beg), 1.f);
    ushort4 o4;
    o4.x = f2b((ax + bx) * inv); o4.y = f2b((ay + by) * inv);
    o4.z = f2b((az + bz) * inv); o4.w = f2b((aw + bw) * inv);
    *(ushort4*)(pooled + (size_t)w * 256 + lane * 4) = o4;
}

// ---------------- object MLP ----------------
__global__ __launch_bounds__(256, 2) void obj_mlp(
    const unsigned short* __restrict__ pooled,
    const unsigned short* __restrict__ w2aT, const float* __restrict__ b2a,
    const unsigned short* __restrict__ w2bT, const float* __restrict__ b2b,
    float* __restrict__ outObj, int O) {
    const int m0 = blockIdx.x * 64;
    const int tid = threadIdx.x;
    const int lane = tid & 63, wid = tid >> 6;
    const int wm = wid >> 1, wn = wid & 1;

    __shared__ unsigned short Abuf[64 * 256];

    {
        const int r = tid >> 2, q = tid & 3;
        int objc = m0 + r; if (objc >= O) objc = O - 1;
        const u16x8* s8 = (const u16x8*)(pooled + (size_t)objc * 256);
        #pragma unroll
        for (int i = 0; i < 8; ++i) {
            u16x8 v = s8[q * 8 + i];
            unsigned byte = r * 512u + (q * 64u + i * 8u) * 2u;
            *(u16x8*)((char*)Abuf + swz(r, byte)) = v;
        }
    }
    __syncthreads();

    f32x4 acc1[2][2][4];
    #pragma unroll
    for (int a = 0; a < 2; ++a)
        #pragma unroll
        for (int b = 0; b < 2; ++b)
            #pragma unroll
            for (int c = 0; c < 4; ++c) acc1[a][b][c] = f32x4{0.f, 0.f, 0.f, 0.f};
    #pragma unroll
    for (int ks = 0; ks < 8; ++ks) {
        const int klane = ks * 32 + ((lane >> 4) << 3);
        s16x8 af[2];
        #pragma unroll
        for (int mi = 0; mi < 2; ++mi) {
            int row = wm * 32 + mi * 16 + (lane & 15);
            af[mi] = *(const s16x8*)((const char*)Abuf + swz(row, row * 512u + klane * 2u));
        }
        #pragma unroll
        for (int nb = 0; nb < 2; ++nb)
            #pragma unroll
            for (int nj = 0; nj < 4; ++nj) {
                int col = nb * 128 + wn * 64 + nj * 16 + (lane & 15);
                s16x8 bf = *(const s16x8*)(w2aT + (long long)col * 256 + klane);
                #pragma unroll
                for (int mi = 0; mi < 2; ++mi)
                    acc1[nb][mi][nj] = __builtin_amdgcn_mfma_f32_16x16x32_bf16(af[mi], bf, acc1[nb][mi][nj], 0, 0, 0);
            }
    }
    __syncthreads();

    #pragma unroll
    for (int nb = 0; nb < 2; ++nb)
        #pragma unroll
        for (int nj = 0; nj < 4; ++nj) {
            int col = nb * 128 + wn * 64 + nj * 16 + (lane & 15);
            float bias = b2a[col];
            #pragma unroll
            for (int mi = 0; mi < 2; ++mi)
                #pragma unroll
                for (int rr = 0; rr < 4; ++rr) {
                    int row = wm * 32 + mi * 16 + ((lane >> 4) << 2) + rr;
                    float v = acc1[nb][mi][nj][rr] + bias;
                    v = v > 0.f ? v : 0.f;
                    *(unsigned short*)((char*)Abuf + swz(row, row * 512u + col * 2u)) = f2b(v);
                }
        }
    __syncthreads();

    f32x4 acc2[2][4];
    #pragma unroll
    for (int b = 0; b < 2; ++b)
        #pragma unroll
        for (int c = 0; c < 4; ++c) acc2[b][c] = f32x4{0.f, 0.f, 0.f, 0.f};
    #pragma unroll
    for (int ks = 0; ks < 8; ++ks) {
        const int klane = ks * 32 + ((lane >> 4) << 3);
        s16x8 af[2];
        #pragma unroll
        for (int mi = 0; mi < 2; ++mi) {
            int row = wm * 32 + mi * 16 + (lane & 15);
            af[mi] = *(const s16x8*)((const char*)Abuf + swz(row, row * 512u + klane * 2u));
        }
        #pragma unroll
        for (int nj = 0; nj < 4; ++nj) {
            int col = wn * 64 + nj * 16 + (lane & 15);
            s16x8 bf = *(const s16x8*)(w2bT + (long long)col * 256 + klane);
            #pragma unroll
            for (int mi = 0; mi < 2; ++mi)
                acc2[mi][nj] = __builtin_amdgcn_mfma_f32_16x16x32_bf16(af[mi], bf, acc2[mi][nj], 0, 0, 0);
        }
    }

    #pragma unroll
    for (int nj = 0; nj < 4; ++nj) {
        int col = wn * 64 + nj * 16 + (lane & 15);
        float bias = b2b[col];
        #pragma unroll
        for (int mi = 0; mi < 2; ++mi)
            #pragma unroll
            for (int rr = 0; rr < 4; ++rr) {
                int row = wm * 32 + mi * 16 + ((lane >> 4) << 2) + rr;
                int o = m0 + row;
                if (o < O) {
                    float v = acc2[mi][nj][rr] + bias;
                    v = v > 0.f ? v : 0.f;
                    outObj[(long long)o * 128 + col] = v;
                }
            }
    }
}

extern "C" void kernel_launch(void* const* d_in, const int* in_sizes, int n_in,
                              void* d_out, int out_size, void* d_ws, size_t ws_size,
                              hipStream_t stream) {
    const float* obj  = (const float*)d_in[0];
    const float* pred = (const float*)d_in[1];
    const int*   edges = (const int*)d_in[2];
    const float* w1a = (const float*)d_in[3];
    const float* b1a = (const float*)d_in[4];
    const float* w1b = (const float*)d_in[5];
    const float* b1b = (const float*)d_in[6];
    const float* w2a = (const float*)d_in[7];
    const float* b2a = (const float*)d_in[8];
    const float* w2b = (const float*)d_in[9];
    const float* b2b = (const float*)d_in[10];

    const int O = in_sizes[0] / 128;
    const int T = in_sizes[1] / 128;

    auto al = [](size_t x) { return (x + 255) & ~(size_t)255; };
    const size_t szEdgeout = (size_t)2 * T * 256 * 2;
    const size_t szPooled  = (size_t)O * 256 * 2;
    const size_t szCnt     = (size_t)O * 4;
    const size_t szRow     = (size_t)(O + 1) * 4;
    const size_t szCsr     = (size_t)2 * T * 4;

    size_t off = 0;
    char* ws = (char*)d_ws;
    unsigned short* edgeout = (unsigned short*)(ws + off); off += al(szEdgeout);
    unsigned short* pooled  = (unsigned short*)(ws + off); off += al(szPooled);
    int* cnt    = (int*)(ws + off); off += al(szCnt);
    int* cursor = (int*)(ws + off); off += al(szCnt);
    int* rowptr = (int*)(ws + off); off += al(szRow);
    int* csr    = (int*)(ws + off); off += al(szCsr);
    unsigned short* w1aT = (unsigned short*)(ws + off); off += (size_t)6 * 16384 * 2;    // 192 KB
    unsigned short* w1bT = (unsigned short*)(ws + off); off += (size_t)10 * 16384 * 2;   // 320 KB
    unsigned short* w2aT = (unsigned short*)(ws + off); off += (size_t)256 * 256 * 2;
    unsigned short* w2bT = (unsigned short*)(ws + off);

    float* outObj = (float*)d_out;
    float* outP   = (float*)d_out + (size_t)O * 128;

    hipMemsetAsync(cnt, 0, szCnt, stream);
    const int prepElems = 98304 + 163840 + 65536 + 32768;
    prep_weights<<<(prepElems + 255) / 256, 256, 0, stream>>>(w1a, w1b, w2a, w2b, w1aT, w1bT, w2aT, w2bT);
    count_kernel_i<<<(T + 255) / 256, 256, 0, stream>>>(edges, cnt, T);
    scan_kernel<<<1, 1024, 0, stream>>>(cnt, rowptr, cursor, O);
    fill_kernel<<<(T + 255) / 256, 256, 0, stream>>>(edges, cursor, csr, T);
    edge_mlp<<<(T + 127) / 128, 512, 0, stream>>>(obj, pred, edges, w1aT, b1a, w1bT, b1b, edgeout, outP, T);
    pool_gather<<<(O + 3) / 4, 256, 0, stream>>>(edgeout, rowptr, csr, pooled, O);
    obj_mlp<<<(O + 63) / 64, 256, 0, stream>>>(pooled, w2aT, b2a, w2bT, b2b, outObj, O);
}

// Round 10
// 930.686 us; speedup vs baseline: 1.0924x; 1.0773x over previous
//
#include <hip/hip_runtime.h>

// GraphConv: edge MLP (384->256->640, bf16 MFMA) + CSR-gather pool + obj MLP (256->256->128)
// Round 10: T4 counted-vmcnt schedule. __syncthreads (which drains vmcnt(0) at every barrier,
// killing the r8/r9 prefetch) replaced by raw s_barrier + exact counted s_waitcnt vmcnt(N):
// DMA for tile t+1 stays IN FLIGHT across the stage-t barrier. Biases hoisted to regs so the
// counted FIFO contains only {4 B-DMA, 4 A-loads, S stores}. T5 setprio around MFMA clusters.

using f32x4 = __attribute__((ext_vector_type(4))) float;
using s16x8 = __attribute__((ext_vector_type(8))) short;
typedef unsigned short u16x8 __attribute__((ext_vector_type(8)));

#define VMCNT0  asm volatile("s_waitcnt vmcnt(0)" ::: "memory")
#define VMCNT4  asm volatile("s_waitcnt vmcnt(4)" ::: "memory")
#define VMCNT16 asm volatile("s_waitcnt vmcnt(16)" ::: "memory")
#define VMCNT32 asm volatile("s_waitcnt vmcnt(32)" ::: "memory")
#define LGKM0   asm volatile("s_waitcnt lgkmcnt(0)" ::: "memory")
#define BAR     __builtin_amdgcn_s_barrier()
#define SCHEDB  __builtin_amdgcn_sched_barrier(0)

static __device__ __forceinline__ unsigned short f2b(float f) {
    unsigned int u = __float_as_uint(f);
    unsigned int r = (u + 0x7fffu + ((u >> 16) & 1u)) >> 16;  // RNE f32->bf16
    return (unsigned short)r;
}

static __device__ __forceinline__ float b2f(unsigned short b) {
    return __uint_as_float(((unsigned)b) << 16);
}

static __device__ __forceinline__ unsigned swz(unsigned row, unsigned byteoff) {
    return byteoff ^ ((row & 7u) << 4);
}

static __device__ __forceinline__ void gload_lds16(const unsigned short* g, unsigned short* l) {
    __builtin_amdgcn_global_load_lds(
        (const __attribute__((address_space(1))) unsigned int*)g,
        (__attribute__((address_space(3))) unsigned int*)l,
        16, 0, 0);
}

// ---------------- weight prep (identical to round 9) ----------------
__global__ void prep_weights(const float* __restrict__ w1a, const float* __restrict__ w1b,
                             const float* __restrict__ w2a, const float* __restrict__ w2b,
                             unsigned short* __restrict__ w1aT, unsigned short* __restrict__ w1bT,
                             unsigned short* __restrict__ w2aT, unsigned short* __restrict__ w2bT) {
    int t = blockIdx.x * blockDim.x + threadIdx.x;
    if (t < 6 * 16384) {
        int kt = t >> 14;
        int rem = t & 16383; int c = rem >> 6, kk = rem & 63;
        unsigned byte = ((unsigned)(c * 128 + kk * 2)) ^ ((c & 7u) << 4);
        *(unsigned short*)((char*)w1aT + (size_t)kt * 32768 + byte) =
            f2b(w1a[(size_t)(kt * 64 + kk) * 256 + c]);
        return;
    }
    t -= 98304;
    if (t < 10 * 16384) {
        int tile = t >> 14; int nc = tile >> 1, kh = tile & 1;
        int rem = t & 16383; int c = rem >> 7, kk = rem & 127;
        unsigned byte = ((unsigned)(c * 256 + kk * 2)) ^ ((c & 7u) << 4);
        *(unsigned short*)((char*)w1bT + (size_t)tile * 32768 + byte) =
            f2b(w1b[(size_t)(kh * 128 + kk) * 640 + nc * 128 + c]);
        return;
    }
    t -= 163840;
    if (t < 65536) { int n = t >> 8, k = t & 255; w2aT[t] = f2b(w2a[k * 256 + n]); return; }
    t -= 65536;
    if (t < 32768) { int n = t >> 8, k = t & 255; w2bT[t] = f2b(w2b[k * 128 + n]); return; }
}

// ---------------- CSR build ----------------
__global__ void count_kernel_i(const int* __restrict__ edges, int* __restrict__ cnt, int T) {
    int e = blockIdx.x * blockDim.x + threadIdx.x;
    if (e < T) {
        atomicAdd(&cnt[edges[2 * (long long)e]], 1);
        atomicAdd(&cnt[edges[2 * (long long)e + 1]], 1);
    }
}

__global__ void scan_kernel(const int* __restrict__ cnt, int* __restrict__ rowptr,
                            int* __restrict__ cursor, int O) {
    __shared__ int sc[1024];
    const int tid = threadIdx.x;
    const int per = (O + 1023) >> 10;
    const int base = tid * per;
    int s = 0;
    for (int i = 0; i < per; ++i) { int j = base + i; if (j < O) s += cnt[j]; }
    sc[tid] = s;
    __syncthreads();
    for (int d = 1; d < 1024; d <<= 1) {
        int v = (tid >= d) ? sc[tid - d] : 0;
        __syncthreads();
        sc[tid] += v;
        __syncthreads();
    }
    int off = sc[tid] - s;
    for (int i = 0; i < per; ++i) {
        int j = base + i;
        if (j < O) { rowptr[j] = off; cursor[j] = off; off += cnt[j]; }
    }
    if (tid == 0) rowptr[O] = sc[1023];
}

__global__ void fill_kernel(const int* __restrict__ edges, int* __restrict__ cursor,
                            int* __restrict__ csr, int T) {
    int e = blockIdx.x * blockDim.x + threadIdx.x;
    if (e < T) {
        int s = edges[2 * (long long)e];
        int o = edges[2 * (long long)e + 1];
        int ps = atomicAdd(&cursor[s], 1); csr[ps] = e;
        int po = atomicAdd(&cursor[o], 1); csr[po] = T + e;
    }
}

// ---------------- edge MLP: BM=128, 8 waves, counted-vmcnt pipeline ----------------
__global__ __launch_bounds__(512, 2) void edge_mlp(
    const float* __restrict__ obj, const float* __restrict__ pred,
    const int* __restrict__ edges,
    const unsigned short* __restrict__ w1aT, const float* __restrict__ b1a,
    const unsigned short* __restrict__ w1bT, const float* __restrict__ b1b,
    unsigned short* __restrict__ edgeout, float* __restrict__ outP, int T) {
    const int m0 = blockIdx.x * 128;
    const int tid = threadIdx.x;
    const int lane = tid & 63, wid = tid >> 6;
    const int wm = wid >> 2, wn = wid & 3;
    const bool evenL = ((lane & 1) == 0);

    __shared__ unsigned short U[65536];
    char* const ldsb = (char*)U;
    unsigned short* const abuf0 = (unsigned short*)(ldsb);
    unsigned short* const abuf1 = (unsigned short*)(ldsb + 16384);
    unsigned short* const Hbuf  = (unsigned short*)(ldsb);
    unsigned short* const bbuf0 = (unsigned short*)(ldsb + 65536);
    unsigned short* const bbuf1 = (unsigned short*)(ldsb + 98304);

    bool okR[4][4];
    #pragma unroll
    for (int mi = 0; mi < 4; ++mi)
        #pragma unroll
        for (int rr = 0; rr < 4; ++rr)
            okR[mi][rr] = (m0 + wm * 64 + mi * 16 + ((lane >> 4) << 2) + rr) < T;

    const int r = tid >> 2;
    const int q = tid & 3;
    int e_r = m0 + r; if (e_r >= T) e_r = T - 1;
    const int sIdx_r = edges[2 * (long long)e_r];
    const int oIdx_r = edges[2 * (long long)e_r + 1];

    // hoist biases into regs: no vmem loads inside the counted region
    float bias1[4], bias2[5][2];
    #pragma unroll
    for (int nj = 0; nj < 4; ++nj) bias1[nj] = b1a[wn * 64 + nj * 16 + (lane & 15)];
    #pragma unroll
    for (int nc = 0; nc < 5; ++nc)
        #pragma unroll
        for (int nj = 0; nj < 2; ++nj)
            bias2[nc][nj] = b1b[nc * 128 + wn * 32 + nj * 16 + (lane & 15)];

    auto aSrc = [&](int kt) -> const float4* {
        const float* s;
        if (kt < 2)      s = obj  + (long long)sIdx_r * 128 + kt * 64;
        else if (kt < 4) s = pred + (long long)e_r   * 128 + (kt - 2) * 64;
        else             s = obj  + (long long)oIdx_r * 128 + (kt - 4) * 64;
        return (const float4*)s;
    };

    auto stageB = [&](const unsigned short* gt, unsigned short* bb) {
        #pragma unroll
        for (int rr4 = 0; rr4 < 4; ++rr4) {
            unsigned off = wid * 4096u + rr4 * 1024u;
            gload_lds16((const unsigned short*)((const char*)gt + off + lane * 16u),
                        (unsigned short*)((char*)bb + off));
        }
    };

    auto writeA = [&](const float4* ap, unsigned short* ab) {
        #pragma unroll
        for (int i = 0; i < 4; ++i) {
            float4 v = ap[i];
            ushort4 pk; pk.x = f2b(v.x); pk.y = f2b(v.y); pk.z = f2b(v.z); pk.w = f2b(v.w);
            unsigned byte = (r * 128u + q * 32u + i * 8u) ^ ((r & 7u) << 4);
            *(ushort4*)((char*)ab + byte) = pk;
        }
    };

    f32x4 acc1[4][4];
    #pragma unroll
    for (int a = 0; a < 4; ++a)
        #pragma unroll
        for (int b = 0; b < 4; ++b) acc1[a][b] = f32x4{0.f, 0.f, 0.f, 0.f};

    auto mfma1 = [&](const unsigned short* ab, const unsigned short* bb) {
        #pragma unroll
        for (int ks = 0; ks < 2; ++ks) {
            const unsigned kk = ks * 32u + ((lane >> 4) << 3);
            s16x8 af[4];
            #pragma unroll
            for (int mi = 0; mi < 4; ++mi) {
                unsigned row = wm * 64u + mi * 16u + (lane & 15);
                af[mi] = *(const s16x8*)((const char*)ab + ((row * 128u + kk * 2u) ^ ((row & 7u) << 4)));
            }
            #pragma unroll
            for (int nj = 0; nj < 4; ++nj) {
                unsigned c = wn * 64u + nj * 16u + (lane & 15);
                s16x8 bf = *(const s16x8*)((const char*)bb + ((c * 128u + kk * 2u) ^ ((c & 7u) << 4)));
                #pragma unroll
                for (int mi = 0; mi < 4; ++mi)
                    acc1[mi][nj] = __builtin_amdgcn_mfma_f32_16x16x32_bf16(af[mi], bf, acc1[mi][nj], 0, 0, 0);
            }
        }
    };

    // ---- prologue: A(0) staged, B(0) in flight, A(1) in flight ----
    float4 ap[4];
    {
        const float4* s4 = aSrc(0);
        #pragma unroll
        for (int i = 0; i < 4; ++i) ap[i] = s4[q * 4 + i];
    }
    writeA(ap, abuf0);                 // compiler inserts its own wait for ap
    stageB(w1aT, bbuf0);               // +4 (B0)
    {
        const float4* s4 = aSrc(1);
        #pragma unroll
        for (int i = 0; i < 4; ++i) ap[i] = s4[q * 4 + i];   // +4 (A1)
    }
    VMCNT4;                            // B0 done; A1 still flying
    LGKM0;
    BAR; SCHEDB;

    // ---- GEMM1: 6 stages; loads for stage k+1 cross barrier k in flight ----
    #pragma unroll
    for (int kt = 0; kt < 6; ++kt) {
        if (kt < 5) stageB(w1aT + (size_t)(kt + 1) * 16384, ((kt + 1) & 1) ? bbuf1 : bbuf0); // +4 B(kt+1)
        else        stageB(w1bT, bbuf0);                                                     // +4 G2 tile0
        __builtin_amdgcn_s_setprio(1);
        mfma1((kt & 1) ? abuf1 : abuf0, (kt & 1) ? bbuf1 : bbuf0);
        __builtin_amdgcn_s_setprio(0);
        if (kt < 5) {
            VMCNT4;                                     // A(kt+1) done (B(kt+1) newest 4 remain)
            writeA(ap, ((kt + 1) & 1) ? abuf1 : abuf0);
            if (kt < 4) {
                const float4* s4 = aSrc(kt + 2);
                #pragma unroll
                for (int i = 0; i < 4; ++i) ap[i] = s4[q * 4 + i];   // +4 A(kt+2)
                VMCNT4;                                 // B(kt+1) done; A(kt+2) flying
            } else {
                VMCNT0;                                 // B(5) done
            }
            LGKM0;
            BAR; SCHEDB;
        }
    }

    // ---- transition: barrier (abuf reads done) -> H write -> barrier (G2 tile0 ready) ----
    LGKM0;
    BAR; SCHEDB;
    #pragma unroll
    for (int nj = 0; nj < 4; ++nj) {
        #pragma unroll
        for (int mi = 0; mi < 4; ++mi)
            #pragma unroll
            for (int rr = 0; rr < 4; ++rr) {
                unsigned row = wm * 64u + mi * 16u + ((lane >> 4) << 2) + rr;
                unsigned col = wn * 64u + nj * 16u + (lane & 15);
                float v = acc1[mi][nj][rr] + bias1[nj];
                v = v > 0.f ? v : 0.f;
                *(unsigned short*)((char*)Hbuf + swz(row, row * 512u + col * 2u)) = f2b(v);
            }
    }
    LGKM0;
    VMCNT0;                            // G2 tile0 landed
    BAR; SCHEDB;

    // ---- GEMM2: 10 stages (5 nc x 2 kh); stores counted, never drained ----
    #pragma unroll
    for (int nc = 0; nc < 5; ++nc) {
        f32x4 acc2[4][2];
        #pragma unroll
        for (int a = 0; a < 4; ++a)
            #pragma unroll
            for (int b = 0; b < 2; ++b) acc2[a][b] = f32x4{0.f, 0.f, 0.f, 0.f};

        #pragma unroll
        for (int kh = 0; kh < 2; ++kh) {
            const int t10 = nc * 2 + kh;
            if (t10 < 9) stageB(w1bT + (size_t)(t10 + 1) * 16384, ((t10 + 1) & 1) ? bbuf1 : bbuf0); // +4
            const unsigned short* bb = (t10 & 1) ? bbuf1 : bbuf0;
            __builtin_amdgcn_s_setprio(1);
            #pragma unroll
            for (int ks = 0; ks < 4; ++ks) {
                const unsigned kkB = ks * 32u + ((lane >> 4) << 3);
                const unsigned kkH = kh * 128u + kkB;
                s16x8 af[4];
                #pragma unroll
                for (int mi = 0; mi < 4; ++mi) {
                    unsigned row = wm * 64u + mi * 16u + (lane & 15);
                    af[mi] = *(const s16x8*)((const char*)Hbuf + swz(row, row * 512u + kkH * 2u));
                }
                #pragma unroll
                for (int nj = 0; nj < 2; ++nj) {
                    unsigned c = wn * 32u + nj * 16u + (lane & 15);
                    s16x8 bf = *(const s16x8*)((const char*)bb + ((c * 256u + kkB * 2u) ^ ((c & 7u) << 4)));
                    #pragma unroll
                    for (int mi = 0; mi < 4; ++mi)
                        acc2[mi][nj] = __builtin_amdgcn_mfma_f32_16x16x32_bf16(af[mi], bf, acc2[mi][nj], 0, 0, 0);
                }
            }
            __builtin_amdgcn_s_setprio(0);

            if (kh == 0) {
                // no epilogue this stage: just ensure B(t10+1) landed, then barrier
                VMCNT0;
                BAR; SCHEDB;
            }
        }

        // epilogue for nc (stores issued AFTER this stage's stageB -> counted waits skip them)
        if (nc == 2) {
            #pragma unroll
            for (int nj = 0; nj < 2; ++nj) {
                int col = nc * 128 + wn * 32 + nj * 16 + (lane & 15);
                #pragma unroll
                for (int mi = 0; mi < 4; ++mi)
                    #pragma unroll
                    for (int rr = 0; rr < 4; ++rr) {
                        int row = wm * 64 + mi * 16 + ((lane >> 4) << 2) + rr;
                        if (okR[mi][rr]) {
                            float v = acc2[mi][nj][rr] + bias2[nc][nj];
                            v = v > 0.f ? v : 0.f;
                            outP[(long long)(m0 + row) * 128 + (col - 256)] = v;   // +32 stores
                        }
                    }
            }
            VMCNT32;                   // 4 oldest (B-DMA) done; stores keep flying
            BAR; SCHEDB;
        } else {
            #pragma unroll
            for (int nj = 0; nj < 2; ++nj) {
                int col = nc * 128 + wn * 32 + nj * 16 + (lane & 15);
                int pc = (nc < 2) ? col : (col - 384);
                int pcb = (lane & 1) ? (pc - 1) : pc;
                #pragma unroll
                for (int mi = 0; mi < 4; ++mi) {
                    float vv[4];
                    #pragma unroll
                    for (int rr = 0; rr < 4; ++rr) {
                        float v = acc2[mi][nj][rr] + bias2[nc][nj];
                        vv[rr] = v > 0.f ? v : 0.f;
                    }
                    float nb0 = __shfl_xor(vv[0], 1);
                    float nb1 = __shfl_xor(vv[1], 1);
                    float nb2 = __shfl_xor(vv[2], 1);
                    float nb3 = __shfl_xor(vv[3], 1);
                    #pragma unroll
                    for (int k = 0; k < 2; ++k) {
                        float lo = evenL ? (k ? vv[1] : vv[0]) : (k ? nb3 : nb2);
                        float hi = evenL ? (k ? nb1 : nb0) : (k ? vv[3] : vv[2]);
                        int rsel = evenL ? k : 2 + k;
                        if (okR[mi][rsel]) {
                            int row = wm * 64 + mi * 16 + ((lane >> 4) << 2) + rsel;
                            size_t e = (size_t)(m0 + row);
                            size_t rid = (nc < 2) ? e : (size_t)T + e;
                            unsigned pk = ((unsigned)f2b(hi) << 16) | f2b(lo);
                            *(unsigned*)(edgeout + rid * 256 + pcb) = pk;          // +16 stores
                        }
                    }
                }
            }
            if (nc < 4) {
                VMCNT16;               // 4 oldest (B-DMA) done; stores keep flying
                BAR; SCHEDB;
            }
            // nc==4: last stage — fire-and-forget, endpgm
        }
    }
}

// ---------------- CSR gather (4-row ILP) ----------------
__global__ __launch_bounds__(256, 4) void pool_gather(
    const unsigned short* __restrict__ edgeout, const int* __restrict__ rowptr,
    const int* __restrict__ csr, unsigned short* __restrict__ pooled, int O) {
    int w = blockIdx.x * 4 + (threadIdx.x >> 6);
    if (w >= O) return;
    const int lane = threadIdx.x & 63;
    const int beg = rowptr[w], end = rowptr[w + 1];
    float ax = 0.f, ay = 0.f, az = 0.f, aw = 0.f;
    float bx = 0.f, by = 0.f, bz = 0.f, bw = 0.f;
    int i = beg;
    for (; i + 3 < end; i += 4) {
        int r0 = csr[i], r1 = csr[i + 1], r2 = csr[i + 2], r3 = csr[i + 3];
        ushort4 v0 = *(const ushort4*)(edgeout + (size_t)r0 * 256 + lane * 4);
        ushort4 v1 = *(const ushort4*)(edgeout + (size_t)r1 * 256 + lane * 4);
        ushort4 v2 = *(const ushort4*)(edgeout + (size_t)r2 * 256 + lane * 4);
        ushort4 v3 = *(const ushort4*)(edgeout + (size_t)r3 * 256 + lane * 4);
        ax += b2f(v0.x); ay += b2f(v0.y); az += b2f(v0.z); aw += b2f(v0.w);
        bx += b2f(v1.x); by += b2f(v1.y); bz += b2f(v1.z); bw += b2f(v1.w);
        ax += b2f(v2.x); ay += b2f(v2.y); az += b2f(v2.z); aw += b2f(v2.w);
        bx += b2f(v3.x); by += b2f(v3.y); bz += b2f(v3.z); bw += b2f(v3.w);
    }
    for (; i < end; ++i) {
        int r0 = csr[i];
        ushort4 v0 = *(const ushort4*)(edgeout + (size_t)r0 * 256 + lane * 4);
        ax += b2f(v0.x); ay += b2f(v0.y); az += b2f(v0.z); aw += b2f(v0.w);
    }
    float inv = 1.f / fmaxf((float)(end - beg), 1.f);
    ushort4 o4;
    o4.x = f2b((ax + bx) * inv); o4.y = f2b((ay + by) * inv);
    o4.z = f2b((az + bz) * inv); o4.w = f2b((aw + bw) * inv);
    *(ushort4*)(pooled + (size_t)w * 256 + lane * 4) = o4;
}

// ---------------- object MLP ----------------
__global__ __launch_bounds__(256, 2) void obj_mlp(
    const unsigned short* __restrict__ pooled,
    const unsigned short* __restrict__ w2aT, const float* __restrict__ b2a,
    const unsigned short* __restrict__ w2bT, const float* __restrict__ b2b,
    float* __restrict__ outObj, int O) {
    const int m0 = blockIdx.x * 64;
    const int tid = threadIdx.x;
    const int lane = tid & 63, wid = tid >> 6;
    const int wm = wid >> 1, wn = wid & 1;

    __shared__ unsigned short Abuf[64 * 256];

    {
        const int r = tid >> 2, q = tid & 3;
        int objc = m0 + r; if (objc >= O) objc = O - 1;
        const u16x8* s8 = (const u16x8*)(pooled + (size_t)objc * 256);
        #pragma unroll
        for (int i = 0; i < 8; ++i) {
            u16x8 v = s8[q * 8 + i];
            unsigned byte = r * 512u + (q * 64u + i * 8u) * 2u;
            *(u16x8*)((char*)Abuf + swz(r, byte)) = v;
        }
    }
    __syncthreads();

    f32x4 acc1[2][2][4];
    #pragma unroll
    for (int a = 0; a < 2; ++a)
        #pragma unroll
        for (int b = 0; b < 2; ++b)
            #pragma unroll
            for (int c = 0; c < 4; ++c) acc1[a][b][c] = f32x4{0.f, 0.f, 0.f, 0.f};
    #pragma unroll
    for (int ks = 0; ks < 8; ++ks) {
        const int klane = ks * 32 + ((lane >> 4) << 3);
        s16x8 af[2];
        #pragma unroll
        for (int mi = 0; mi < 2; ++mi) {
            int row = wm * 32 + mi * 16 + (lane & 15);
            af[mi] = *(const s16x8*)((const char*)Abuf + swz(row, row * 512u + klane * 2u));
        }
        #pragma unroll
        for (int nb = 0; nb < 2; ++nb)
            #pragma unroll
            for (int nj = 0; nj < 4; ++nj) {
                int col = nb * 128 + wn * 64 + nj * 16 + (lane & 15);
                s16x8 bf = *(const s16x8*)(w2aT + (long long)col * 256 + klane);
                #pragma unroll
                for (int mi = 0; mi < 2; ++mi)
                    acc1[nb][mi][nj] = __builtin_amdgcn_mfma_f32_16x16x32_bf16(af[mi], bf, acc1[nb][mi][nj], 0, 0, 0);
            }
    }
    __syncthreads();

    #pragma unroll
    for (int nb = 0; nb < 2; ++nb)
        #pragma unroll
        for (int nj = 0; nj < 4; ++nj) {
            int col = nb * 128 + wn * 64 + nj * 16 + (lane & 15);
            float bias = b2a[col];
            #pragma unroll
            for (int mi = 0; mi < 2; ++mi)
                #pragma unroll
                for (int rr = 0; rr < 4; ++rr) {
                    int row = wm * 32 + mi * 16 + ((lane >> 4) << 2) + rr;
                    float v = acc1[nb][mi][nj][rr] + bias;
                    v = v > 0.f ? v : 0.f;
                    *(unsigned short*)((char*)Abuf + swz(row, row * 512u + col * 2u)) = f2b(v);
                }
        }
    __syncthreads();

    f32x4 acc2[2][4];
    #pragma unroll
    for (int b = 0; b < 2; ++b)
        #pragma unroll
        for (int c = 0; c < 4; ++c) acc2[b][c] = f32x4{0.f, 0.f, 0.f, 0.f};
    #pragma unroll
    for (int ks = 0; ks < 8; ++ks) {
        const int klane = ks * 32 + ((lane >> 4) << 3);
        s16x8 af[2];
        #pragma unroll
        for (int mi = 0; mi < 2; ++mi) {
            int row = wm * 32 + mi * 16 + (lane & 15);
            af[mi] = *(const s16x8*)((const char*)Abuf + swz(row, row * 512u + klane * 2u));
        }
        #pragma unroll
        for (int nj = 0; nj < 4; ++nj) {
            int col = wn * 64 + nj * 16 + (lane & 15);
            s16x8 bf = *(const s16x8*)(w2bT + (long long)col * 256 + klane);
            #pragma unroll
            for (int mi = 0; mi < 2; ++mi)
                acc2[mi][nj] = __builtin_amdgcn_mfma_f32_16x16x32_bf16(af[mi], bf, acc2[mi][nj], 0, 0, 0);
        }
    }

    #pragma unroll
    for (int nj = 0; nj < 4; ++nj) {
        int col = wn * 64 + nj * 16 + (lane & 15);
        float bias = b2b[col];
        #pragma unroll
        for (int mi = 0; mi < 2; ++mi)
            #pragma unroll
            for (int rr = 0; rr < 4; ++rr) {
                int row = wm * 32 + mi * 16 + ((lane >> 4) << 2) + rr;
                int o = m0 + row;
                if (o < O) {
                    float v = acc2[mi][nj][rr] + bias;
                    v = v > 0.f ? v : 0.f;
                    outObj[(long long)o * 128 + col] = v;
                }
            }
    }
}

extern "C" void kernel_launch(void* const* d_in, const int* in_sizes, int n_in,
                              void* d_out, int out_size, void* d_ws, size_t ws_size,
                              hipStream_t stream) {
    const float* obj  = (const float*)d_in[0];
    const float* pred = (const float*)d_in[1];
    const int*   edges = (const int*)d_in[2];
    const float* w1a = (const float*)d_in[3];
    const float* b1a = (const float*)d_in[4];
    const float* w1b = (const float*)d_in[5];
    const float* b1b = (const float*)d_in[6];
    const float* w2a = (const float*)d_in[7];
    const float* b2a = (const float*)d_in[8];
    const float* w2b = (const float*)d_in[9];
    const float* b2b = (const float*)d_in[10];

    const int O = in_sizes[0] / 128;
    const int T = in_sizes[1] / 128;

    auto al = [](size_t x) { return (x + 255) & ~(size_t)255; };
    const size_t szEdgeout = (size_t)2 * T * 256 * 2;
    const size_t szPooled  = (size_t)O * 256 * 2;
    const size_t szCnt     = (size_t)O * 4;
    const size_t szRow     = (size_t)(O + 1) * 4;
    const size_t szCsr     = (size_t)2 * T * 4;

    size_t off = 0;
    char* ws = (char*)d_ws;
    unsigned short* edgeout = (unsigned short*)(ws + off); off += al(szEdgeout);
    unsigned short* pooled  = (unsigned short*)(ws + off); off += al(szPooled);
    int* cnt    = (int*)(ws + off); off += al(szCnt);
    int* cursor = (int*)(ws + off); off += al(szCnt);
    int* rowptr = (int*)(ws + off); off += al(szRow);
    int* csr    = (int*)(ws + off); off += al(szCsr);
    unsigned short* w1aT = (unsigned short*)(ws + off); off += (size_t)6 * 16384 * 2;
    unsigned short* w1bT = (unsigned short*)(ws + off); off += (size_t)10 * 16384 * 2;
    unsigned short* w2aT = (unsigned short*)(ws + off); off += (size_t)256 * 256 * 2;
    unsigned short* w2bT = (unsigned short*)(ws + off);

    float* outObj = (float*)d_out;
    float* outP   = (float*)d_out + (size_t)O * 128;

    hipMemsetAsync(cnt, 0, szCnt, stream);
    const int prepElems = 98304 + 163840 + 65536 + 32768;
    prep_weights<<<(prepElems + 255) / 256, 256, 0, stream>>>(w1a, w1b, w2a, w2b, w1aT, w1bT, w2aT, w2bT);
    count_kernel_i<<<(T + 255) / 256, 256, 0, stream>>>(edges, cnt, T);
    scan_kernel<<<1, 1024, 0, stream>>>(cnt, rowptr, cursor, O);
    fill_kernel<<<(T + 255) / 256, 256, 0, stream>>>(edges, cursor, csr, T);
    edge_mlp<<<(T + 127) / 128, 512, 0, stream>>>(obj, pred, edges, w1aT, b1a, w1bT, b1b, edgeout, outP, T);
    pool_gather<<<(O + 3) / 4, 256, 0, stream>>>(edgeout, rowptr, csr, pooled, O);
    obj_mlp<<<(O + 63) / 64, 256, 0, stream>>>(pooled, w2aT, b2a, w2bT, b2b, outObj, O);
}